// Round 4
// baseline (309.432 us; speedup 1.0000x reference)
//
#include <hip/hip_runtime.h>
#include <hip/hip_bf16.h>
#include <math.h>

// ip (8, 256, 128, 128) fp32 -> DCT-III along channels:
// out[b,c,p] = ip[b,0,p] + 2*sum_{k>0} ip[b,k,p] * cos(pi*k*(2c+1)/512)
#define NB   8
#define NC   256
#define NHW  (128 * 128)

typedef __attribute__((ext_vector_type(4))) float f32x4;
typedef __attribute__((ext_vector_type(8))) short bf16x8;

__device__ __forceinline__ unsigned f2bf_lo(float f) {
    unsigned u = __builtin_bit_cast(unsigned, f);
    u += 0x7fffu + ((u >> 16) & 1u);
    return u >> 16;
}
__device__ __forceinline__ unsigned f2bf_hi(float f) {
    unsigned u = __builtin_bit_cast(unsigned, f);
    u += 0x7fffu + ((u >> 16) & 1u);
    return u & 0xffff0000u;
}

// DCT-III coefficient matrix, bf16 row-major [c][k], exact int angle reduction.
__global__ void coef_kernel(unsigned short* __restrict__ coef) {
    int idx = blockIdx.x * 256 + threadIdx.x;
    int c = idx >> 8;
    int k = idx & 255;
    int t = (k * (2 * c + 1)) & 1023;
    float v = (k == 0) ? 1.0f : 2.0f * cosf((float)t * (float)(M_PI / 512.0));
    coef[idx] = (unsigned short)f2bf_lo(v);
}

// Barrier-free, LDS-free GEMM. Block = 256 threads = 4 independent waves.
// Wave w: c rows w*64..w*64+63 (4 mt tiles), p cols p0..p0+31 (2 nt tiles).
// B fragments gathered DIRECTLY from global X: B[n=lane&15][k=quad*8+j]
// -> register j = one dword load X[(k)*NHW + p0 + nt*16 + m16], coalesced
// 64 B across each 16-lane group. fp32->bf16 pack in registers.
// A fragments (L2-hot 128 KB coef): b128 loads A[m=lane&15][k=quad*8..+7].
__global__ __launch_bounds__(256, 4)
void dct_gemm(const float* __restrict__ X, const unsigned short* __restrict__ Mcoef,
              float* __restrict__ Out) {
    const int tid  = threadIdx.x;
    const int lane = tid & 63;
    const int wm   = tid >> 6;        // 0..3 -> c quarter
    const int m16  = lane & 15;
    const int quad = lane >> 4;

    const int p0 = blockIdx.x * 32;
    const float* Xb = X + (size_t)blockIdx.y * (NC * NHW);
    float* Ob = Out + (size_t)blockIdx.y * (NC * NHW);

    // per-lane bases
    const float* xlane = Xb + (size_t)(quad * 8) * NHW + p0 + m16;  // + (s*32+j)*NHW + nt*16
    const unsigned short* Abase = Mcoef + (wm * 64 + m16) * NC + quad * 8;

    f32x4 acc[4][2];
#pragma unroll
    for (int i = 0; i < 4; i++)
#pragma unroll
        for (int j = 0; j < 2; j++) acc[i][j] = (f32x4){0.f, 0.f, 0.f, 0.f};

    // ---- software pipeline, 1 deep; all loads independent ----
    float bv[2][8];
    bf16x8 afr[4];
#pragma unroll
    for (int nt = 0; nt < 2; nt++)
#pragma unroll
        for (int j = 0; j < 8; j++) bv[nt][j] = xlane[j * NHW + nt * 16];
#pragma unroll
    for (int mt = 0; mt < 4; mt++)
        afr[mt] = *(const bf16x8*)(Abase + mt * 16 * NC);

#pragma unroll
    for (int s = 0; s < 8; ++s) {
        // prefetch step s+1 (folds away on last iter)
        float bn[2][8];
        bf16x8 an[4];
        if (s < 7) {
            const int k1 = (s + 1) * 32;
#pragma unroll
            for (int nt = 0; nt < 2; nt++)
#pragma unroll
                for (int j = 0; j < 8; j++) bn[nt][j] = xlane[(k1 + j) * NHW + nt * 16];
#pragma unroll
            for (int mt = 0; mt < 4; mt++)
                an[mt] = *(const bf16x8*)(Abase + mt * 16 * NC + k1);
        }

        // pack current B to bf16
        bf16x8 bfr[2];
#pragma unroll
        for (int nt = 0; nt < 2; nt++) {
            int4 pk;
            pk.x = (int)(f2bf_lo(bv[nt][0]) | f2bf_hi(bv[nt][1]));
            pk.y = (int)(f2bf_lo(bv[nt][2]) | f2bf_hi(bv[nt][3]));
            pk.z = (int)(f2bf_lo(bv[nt][4]) | f2bf_hi(bv[nt][5]));
            pk.w = (int)(f2bf_lo(bv[nt][6]) | f2bf_hi(bv[nt][7]));
            bfr[nt] = __builtin_bit_cast(bf16x8, pk);
        }

#pragma unroll
        for (int mt = 0; mt < 4; mt++)
#pragma unroll
            for (int nt = 0; nt < 2; nt++)
                acc[mt][nt] = __builtin_amdgcn_mfma_f32_16x16x32_bf16(
                    afr[mt], bfr[nt], acc[mt][nt], 0, 0, 0);

        if (s < 7) {
#pragma unroll
            for (int nt = 0; nt < 2; nt++)
#pragma unroll
                for (int j = 0; j < 8; j++) bv[nt][j] = bn[nt][j];
#pragma unroll
            for (int mt = 0; mt < 4; mt++) afr[mt] = an[mt];
        }
    }

    // ---- epilogue: D layout col(p) = lane&15, row(c) = quad*4 + r ----
#pragma unroll
    for (int mt = 0; mt < 4; mt++) {
#pragma unroll
        for (int nt = 0; nt < 2; nt++) {
            int cc = wm * 64 + mt * 16 + quad * 4;
            int pp = p0 + nt * 16 + m16;
            float* o = Ob + (size_t)cc * NHW + pp;
#pragma unroll
            for (int r = 0; r < 4; r++)
                o[(size_t)r * NHW] = acc[mt][nt][r];
        }
    }
}

extern "C" void kernel_launch(void* const* d_in, const int* in_sizes, int n_in,
                              void* d_out, int out_size, void* d_ws, size_t ws_size,
                              hipStream_t stream) {
    const float* ip = (const float*)d_in[0];
    float* out = (float*)d_out;
    unsigned short* coef = (unsigned short*)d_ws;   // 128 KB scratch (re-poisoned each launch)

    coef_kernel<<<dim3(256), dim3(256), 0, stream>>>(coef);

    dim3 grid(NHW / 32, NB);   // (512, 8) = 4096 blocks x 256 threads
    dct_gemm<<<grid, dim3(256), 0, stream>>>(ip, coef, out);
}

// Round 5
// 276.478 us; speedup vs baseline: 1.1192x; 1.1192x over previous
//
#include <hip/hip_runtime.h>
#include <hip/hip_bf16.h>
#include <math.h>

// ip (8, 256, 128, 128) fp32 -> DCT-III along channels:
// out[b,c,p] = ip[b,0,p] + 2*sum_{k>0} ip[b,k,p] * cos(pi*k*(2c+1)/512)
//
// Formulated as D[p][c] = sum_k X^T[p][k] * M^T[k][c]  (role-swapped GEMM)
// so that BOTH global loads (X, float4 along p) and global stores (dwordx4
// along p, since D rows = p live in the 4 acc registers) are 16 B/lane.
// R1-R4 post-mortem: 4 B/lane vmem instructions cap at ~1/4 of HBM rate.
#define NB   8
#define NC   256
#define NHW  (128 * 128)
#define BN   128        // p-tile per block

typedef __attribute__((ext_vector_type(4))) float f32x4;
typedef __attribute__((ext_vector_type(8))) short bf16x8;

__device__ __forceinline__ unsigned f2bf_lo(float f) {
    unsigned u = __builtin_bit_cast(unsigned, f);
    u += 0x7fffu + ((u >> 16) & 1u);
    return u >> 16;
}
__device__ __forceinline__ unsigned f2bf_hi(float f) {
    unsigned u = __builtin_bit_cast(unsigned, f);
    u += 0x7fffu + ((u >> 16) & 1u);
    return u & 0xffff0000u;
}

// DCT-III coefficient matrix, bf16 row-major [c][k], exact int angle reduction.
__global__ void coef_kernel(unsigned short* __restrict__ coef) {
    int idx = blockIdx.x * 256 + threadIdx.x;
    int c = idx >> 8;
    int k = idx & 255;
    int t = (k * (2 * c + 1)) & 1023;
    float v = (k == 0) ? 1.0f : 2.0f * cosf((float)t * (float)(M_PI / 512.0));
    coef[idx] = (unsigned short)f2bf_lo(v);
}

// LDS: Xlds[p][k] bf16, 128 rows x 512 B. k in 8-B chunks (k8 = k/4),
// chunk XOR-swizzled with bits of p so that both the b64 staging writes
// (32 lanes, p = 4*pl+s) and the b128 fragment reads (16 lanes, p = base+m16)
// spread across >=16 banks (2-way = free).
__device__ __forceinline__ int xoff(int p, int k8) {
    return p * 512 + (((k8 ^ (((p >> 2) & 7) << 1))) << 3);
}

__global__ __launch_bounds__(1024, 4)
void dct_gemm(const float* __restrict__ X, const unsigned short* __restrict__ Mcoef,
              float* __restrict__ Out) {
    __shared__ unsigned char Xlds[BN * 512];   // 64 KB

    const int tid = threadIdx.x;
    const int p0  = blockIdx.x * BN;
    const float* Xb = X + (size_t)blockIdx.y * (NC * NHW);
    float* Ob = Out + (size_t)blockIdx.y * (NC * NHW);

    // ---- stage X tile (128 p x 256 k) : float4 loads along p, in-register
    //      4x4 transpose, bf16 pack, swizzled b64 LDS writes ----
    {
        const int pl = tid & 31;        // p-group of 4
        const int kq = tid >> 5;        // 0..31 -> k-group of 4
        const float* xsrc = Xb + p0 + pl * 4;
#pragma unroll
        for (int o = 0; o < 2; ++o) {
            const int k0 = o * 128 + kq * 4;
            f32x4 L[4];
#pragma unroll
            for (int r = 0; r < 4; ++r)
                L[r] = *(const f32x4*)(xsrc + (size_t)(k0 + r) * NHW);
            const int k8 = k0 >> 2;
#pragma unroll
            for (int s = 0; s < 4; ++s) {
                unsigned w0 = f2bf_lo(L[0][s]) | f2bf_hi(L[1][s]);
                unsigned w1 = f2bf_lo(L[2][s]) | f2bf_hi(L[3][s]);
                *(int2*)(Xlds + xoff(pl * 4 + s, k8)) = (int2){(int)w0, (int)w1};
            }
        }
    }
    __syncthreads();   // the only barrier

    // ---- compute: 16 waves = 4 p-quarters (32) x 4 c-quarters (64) ----
    const int lane = tid & 63;
    const int wave = tid >> 6;
    const int wp   = wave & 3;        // p quarter: 32 rows
    const int wc   = wave >> 2;       // c quarter: 64 cols
    const int m16  = lane & 15;
    const int quad = lane >> 4;

    f32x4 acc[2][4];
#pragma unroll
    for (int i = 0; i < 2; i++)
#pragma unroll
        for (int j = 0; j < 4; j++) acc[i][j] = (f32x4){0.f, 0.f, 0.f, 0.f};

    // A = X^T from LDS: A[m=lane&15 -> p][k=quad*8+j]
    // B = M^T from global (L2-hot 128 KB): B[k=quad*8+j][n=lane&15 -> c]
    //   element B[k][c] = M[c][k] -> b128 at Mcoef + c*NC + k
    const unsigned short* Bbase = Mcoef + (wc * 64 + m16) * NC + quad * 8;

#pragma unroll
    for (int s = 0; s < 8; ++s) {          // k-step of 32
        bf16x8 afr[2], bfr[4];
#pragma unroll
        for (int mt = 0; mt < 2; mt++) {
            int p = wp * 32 + mt * 16 + m16;
            int pos = (s * 8 + quad * 2) ^ ((((p >> 2) & 7)) << 1);
            afr[mt] = *(const bf16x8*)(Xlds + p * 512 + (pos << 3));
        }
#pragma unroll
        for (int nt = 0; nt < 4; nt++)
            bfr[nt] = *(const bf16x8*)(Bbase + nt * 16 * NC + s * 32);
#pragma unroll
        for (int mt = 0; mt < 2; mt++)
#pragma unroll
            for (int nt = 0; nt < 4; nt++)
                acc[mt][nt] = __builtin_amdgcn_mfma_f32_16x16x32_bf16(
                    afr[mt], bfr[nt], acc[mt][nt], 0, 0, 0);
    }

    // ---- epilogue: D[m=p][n=c]; lane holds rows m = quad*4 + r, col n=m16.
    //      The 4 acc floats are 4 consecutive p -> one dwordx4 store each. ----
#pragma unroll
    for (int mt = 0; mt < 2; mt++) {
#pragma unroll
        for (int nt = 0; nt < 4; nt++) {
            int cc = wc * 64 + nt * 16 + m16;
            int pp = p0 + wp * 32 + mt * 16 + quad * 4;
            *(f32x4*)(Ob + (size_t)cc * NHW + pp) = acc[mt][nt];
        }
    }
}

extern "C" void kernel_launch(void* const* d_in, const int* in_sizes, int n_in,
                              void* d_out, int out_size, void* d_ws, size_t ws_size,
                              hipStream_t stream) {
    const float* ip = (const float*)d_in[0];
    float* out = (float*)d_out;
    unsigned short* coef = (unsigned short*)d_ws;   // 128 KB scratch (re-poisoned each launch)

    coef_kernel<<<dim3(256), dim3(256), 0, stream>>>(coef);

    dim3 grid(NHW / BN, NB);   // (128, 8) = 1024 blocks x 1024 threads
    dct_gemm<<<grid, dim3(1024), 0, stream>>>(ip, coef, out);
}